// Round 2
// baseline (178.043 us; speedup 1.0000x reference)
//
#include <hip/hip_runtime.h>
#include <hip/hip_bf16.h>

typedef short short8 __attribute__((ext_vector_type(8)));
typedef float floatx4 __attribute__((ext_vector_type(4)));
typedef unsigned uintx4 __attribute__((ext_vector_type(4)));

#define HWSZ 16384   // 128*128
#define WD 128
#define CD 64
#define OD 64
#define XSTR 72      // bf16 LDS row stride (144B = 9 granules, uniform b128 bank classes)
#define L2E2 2.8853900817779268f   // 2*log2(e)

__device__ __forceinline__ short f2bf(float f) {
    unsigned u = __builtin_bit_cast(unsigned, f);
    u += 0x7FFFu + ((u >> 16) & 1u);     // RNE
    return (short)(u >> 16);
}

// pack two floats -> packed bf16x2 (RNE; compiler emits v_cvt_pk_bf16_f32)
__device__ __forceinline__ unsigned pack2bf(float a, float b) {
    __hip_bfloat162 h = __float22bfloat162_rn(float2{a, b});
    unsigned u;
    __builtin_memcpy(&u, &h, 4);
    return u;
}

__device__ __forceinline__ float bf2f(short s) {
    return __builtin_bit_cast(float, ((unsigned)(unsigned short)s) << 16);
}

// one-time repack: wgt[o][c][k] fp32 -> wp[k][o][c] bf16, PRE-DOUBLED (folds the
// 2 of 1+tanh = 2*sigmoid(2s) into w; exact in bf16). Coalesced writes.
__global__ void prepack_w(const float* __restrict__ wgt, unsigned short* __restrict__ wp) {
    int idx = blockIdx.x * 256 + threadIdx.x;     // 9*64*64 = 36864
    if (idx < 9 * 64 * 64) {
        int k = idx >> 12, o = (idx >> 6) & 63, c = idx & 63;
        wp[idx] = (unsigned short)f2bf(2.0f * wgt[o * 576 + c * 9 + k]);
    }
}

__global__ __launch_bounds__(256, 5)
void paka_kernel(const float* __restrict__ x, const float* __restrict__ gc,
                 const float* __restrict__ gs, const float* __restrict__ wgt,
                 const unsigned short* __restrict__ wp, float* __restrict__ out)
{
    // Only LDS use: bf16 x row, slot = w+1, slots 0/129 are zero pad. 18.7 KB.
    __shared__ short xl[130 * XSTR];

    const int tid  = threadIdx.x;
    const int wave = tid >> 6;
    const int lane = tid & 63;
    const int b = blockIdx.x >> 7;      // 8 batches
    const int h = blockIdx.x & 127;     // 128 rows

    const float* xb  = x  + (size_t)b * CD * HWSZ;
    const float* gcb = gc + (size_t)b * CD * HWSZ;
    const float* gsb = gs + (size_t)b * 9 * HWSZ;

    const int row = lane & 15;
    const int q   = lane >> 4;
    const int mt0 = wave * 2;

    // ---- prefetch eg = exp2(2log2e * gc[c][h][p]) for this lane's MFMA elements
    float eg[2][2][8];
    #pragma unroll
    for (int mt = 0; mt < 2; ++mt) {
        int p = (mt0 + mt) * 16 + row;
        #pragma unroll
        for (int ks = 0; ks < 2; ++ks)
            #pragma unroll
            for (int j = 0; j < 8; ++j) {
                int c = ks * 32 + q * 8 + j;
                eg[mt][ks][j] = __builtin_amdgcn_exp2f(gcb[(size_t)c * HWSZ + h * WD + p] * L2E2);
            }
    }
    // ---- prefetch esv = exp2(2log2e * gs[k][h][p]) for all 9 taps
    float esv[9][2];
    #pragma unroll
    for (int k = 0; k < 9; ++k)
        #pragma unroll
        for (int mt = 0; mt < 2; ++mt) {
            int p = (mt0 + mt) * 16 + row;
            esv[k][mt] = __builtin_amdgcn_exp2f(gsb[k * HWSZ + h * WD + p] * L2E2);
        }

    // zero the two pad rows of xl (w = -1 and w = 128) once
    if (tid < 32)
        *(unsigned*)&xl[0 * XSTR + tid * 2] = 0u;
    else if (tid < 64)
        *(unsigned*)&xl[129 * XSTR + (tid - 32) * 2] = 0u;

    floatx4 acc[2][4];
    #pragma unroll
    for (int i = 0; i < 2; ++i)
        #pragma unroll
        for (int n = 0; n < 4; ++n)
            acc[i][n] = (floatx4){0.f, 0.f, 0.f, 0.f};

    #pragma unroll
    for (int dh = 0; dh < 3; ++dh) {
        const int hh = h + dh - 1;
        if ((unsigned)hh >= 128u) continue;   // block-uniform: taps contribute zero

        __syncthreads();   // previous MFMA phase done reading xl

        // ---- stage x row hh: each thread owns 1 pixel x 8 consecutive channels.
        // Global: scalar loads, lanes 0..31 consecutive p -> 128B segments.
        // LDS: one ds_write_b128/it, uniform 8-lane granule classes (conflict-free).
        {
            const int g = tid >> 5;                  // channel-group 0..7 (c = 8g..8g+7)
            const float* xg = xb + (size_t)(8 * g) * HWSZ + hh * WD;
            #pragma unroll
            for (int it = 0; it < 4; ++it) {
                int p = it * 32 + (tid & 31);
                uintx4 pv;
                #pragma unroll
                for (int cc = 0; cc < 4; ++cc) {
                    float a  = xg[(size_t)(2 * cc) * HWSZ + p];
                    float b2 = xg[(size_t)(2 * cc + 1) * HWSZ + p];
                    pv[cc] = pack2bf(a, b2);
                }
                *(uintx4*)&xl[(p + 1) * XSTR + g * 8] = pv;
            }
        }

        __syncthreads();

        // ---- 3 dw taps share this staging; W fragments come straight from
        // global wp (73.7 KB, L2/L1-resident, shared by all blocks): no wl LDS.
        #pragma unroll
        for (int dw = 0; dw < 3; ++dw) {
            const int k = dh * 3 + dw;
            const unsigned short* wk = wp ? wp + k * 4096 : nullptr;
            #pragma unroll
            for (int ks = 0; ks < 2; ++ks) {
                short8 af[2];
                #pragma unroll
                for (int mt = 0; mt < 2; ++mt) {
                    int wslot = (mt0 + mt) * 16 + row + dw;   // = p + dw, xl slot of w=p+dw-1
                    short8 raw = *(const short8*)&xl[wslot * XSTR + ks * 32 + q * 8];
                    float es = esv[k][mt];
                    #pragma unroll
                    for (int jj = 0; jj < 4; ++jj) {
                        float d0 = fmaf(eg[mt][ks][2 * jj],     es, 1.0f);
                        float d1 = fmaf(eg[mt][ks][2 * jj + 1], es, 1.0f);
                        float r0 = __builtin_amdgcn_rcpf(d0);
                        float r1 = __builtin_amdgcn_rcpf(d1);
                        float x0 = bf2f(raw[2 * jj]);
                        float x1 = bf2f(raw[2 * jj + 1]);
                        float t0 = fmaf(-x0, r0, x0);   // x * u/(1+u), the 2 lives in w
                        float t1 = fmaf(-x1, r1, x1);
                        ((unsigned*)&af[mt])[jj] = pack2bf(t0, t1);
                    }
                }
                #pragma unroll
                for (int nt = 0; nt < 4; ++nt) {
                    short8 bv;
                    if (wk) {
                        bv = *(const short8*)&wk[(nt * 16 + row) * 64 + ks * 32 + q * 8];
                    } else {
                        #pragma unroll
                        for (int j = 0; j < 8; ++j) {
                            int o = nt * 16 + row, c = ks * 32 + q * 8 + j;
                            bv[j] = f2bf(2.0f * wgt[o * 576 + c * 9 + k]);
                        }
                    }
                    // SWAPPED operands: D[o][p] = sum_c W'[o][c] * X'[c][p]
                    // col(lane&15) = p  -> lane-contiguous pixels -> direct stores
                    acc[0][nt] = __builtin_amdgcn_mfma_f32_16x16x32_bf16(bv, af[0], acc[0][nt], 0, 0, 0);
                    acc[1][nt] = __builtin_amdgcn_mfma_f32_16x16x32_bf16(bv, af[1], acc[1][nt], 0, 0, 0);
                }
            }
        }
    }

    // ---- epilogue: direct global stores, no LDS.
    // D layout (swapped): col = lane&15 = p - (mt0+mt)*16, row = o-local = q*4 + r.
    float* outb = out + ((size_t)b * OD) * HWSZ + h * WD;
    #pragma unroll
    for (int mt = 0; mt < 2; ++mt) {
        int p = (mt0 + mt) * 16 + row;
        #pragma unroll
        for (int nt = 0; nt < 4; ++nt) {
            #pragma unroll
            for (int r = 0; r < 4; ++r) {
                int o = nt * 16 + q * 4 + r;
                outb[(size_t)o * HWSZ + p] = acc[mt][nt][r];
            }
        }
    }
}

extern "C" void kernel_launch(void* const* d_in, const int* in_sizes, int n_in,
                              void* d_out, int out_size, void* d_ws, size_t ws_size,
                              hipStream_t stream) {
    const float* x   = (const float*)d_in[0];
    const float* gcp = (const float*)d_in[1];
    const float* gsp = (const float*)d_in[2];
    const float* wgt = (const float*)d_in[3];
    float* out = (float*)d_out;

    const bool use_wp = ws_size >= (size_t)(9 * 64 * 64 * sizeof(unsigned short));
    unsigned short* wp = use_wp ? (unsigned short*)d_ws : nullptr;
    if (use_wp)
        prepack_w<<<dim3(144), dim3(256), 0, stream>>>(wgt, wp);
    paka_kernel<<<dim3(1024), dim3(256), 0, stream>>>(x, gcp, gsp, wgt, wp, out);
}

// Round 3
// 139.462 us; speedup vs baseline: 1.2766x; 1.2766x over previous
//
#include <hip/hip_runtime.h>
#include <hip/hip_bf16.h>

typedef short short8 __attribute__((ext_vector_type(8)));
typedef float floatx4 __attribute__((ext_vector_type(4)));
typedef unsigned uintx4 __attribute__((ext_vector_type(4)));

#define HWSZ 16384   // 128*128
#define WD 128
#define CD 64
#define OD 64
#define XSTR 72      // bf16 LDS row stride (144B = 9 granules): <=2-way banks on b128
#define OSTR 136     // fp32 epilogue stride: granule = 2*row+q on writes, 2o+j on reads -> <=2-way (free)
#define L2E2 2.8853900817779268f   // 2*log2(e)

__device__ __forceinline__ short f2bf(float f) {
    unsigned u = __builtin_bit_cast(unsigned, f);
    u += 0x7FFFu + ((u >> 16) & 1u);     // RNE
    return (short)(u >> 16);
}

// pack two floats -> packed bf16x2 (RNE; compiler emits v_cvt_pk_bf16_f32)
__device__ __forceinline__ unsigned pack2bf(float a, float b) {
    __hip_bfloat162 h = __float22bfloat162_rn(float2{a, b});
    unsigned u;
    __builtin_memcpy(&u, &h, 4);
    return u;
}

__device__ __forceinline__ float bf2f(short s) {
    return __builtin_bit_cast(float, ((unsigned)(unsigned short)s) << 16);
}

// one-time repack: wgt[o][c][k] fp32 -> wp[k][o][c] bf16, PRE-DOUBLED (folds the
// 2 of 1+tanh = 2*sigmoid(2s) into w; exact in bf16). Coalesced writes.
__global__ void prepack_w(const float* __restrict__ wgt, unsigned short* __restrict__ wp) {
    int idx = blockIdx.x * 256 + threadIdx.x;     // 9*64*64 = 36864
    if (idx < 9 * 64 * 64) {
        int k = idx >> 12, o = (idx >> 6) & 63, c = idx & 63;
        wp[idx] = (unsigned short)f2bf(2.0f * wgt[o * 576 + c * 9 + k]);
    }
}

__global__ __launch_bounds__(256, 3)
void paka_kernel(const float* __restrict__ x, const float* __restrict__ gc,
                 const float* __restrict__ gs, const float* __restrict__ wgt,
                 const unsigned short* __restrict__ wp, float* __restrict__ out)
{
    __shared__ union {
        struct {
            short xl[130 * XSTR];     // raw x (bf16), slot = w+1, slots 0/129 = zero pad
            short wl[3][64 * XSTR];   // 2*W bf16 for the 3 dw-taps of current dh
        } s;
        float o[64 * OSTR];           // epilogue transpose buffer (34.8 KB)
    } lds;

    const int tid  = threadIdx.x;
    const int wave = tid >> 6;
    const int lane = tid & 63;
    const int b = blockIdx.x >> 7;      // 8 batches
    const int h = blockIdx.x & 127;     // 128 rows

    const float* xb  = x  + (size_t)b * CD * HWSZ;
    const float* gcb = gc + (size_t)b * CD * HWSZ;
    const float* gsb = gs + (size_t)b * 9 * HWSZ;

    const int row = lane & 15;
    const int q   = lane >> 4;
    const int mt0 = wave * 2;

    // ---- prefetch eg = exp2(2log2e * gc[c][h][p]) for this lane's MFMA elements
    float eg[2][2][8];
    #pragma unroll
    for (int mt = 0; mt < 2; ++mt) {
        int p = (mt0 + mt) * 16 + row;
        #pragma unroll
        for (int ks = 0; ks < 2; ++ks)
            #pragma unroll
            for (int j = 0; j < 8; ++j) {
                int c = ks * 32 + q * 8 + j;
                eg[mt][ks][j] = __builtin_amdgcn_exp2f(gcb[(size_t)c * HWSZ + h * WD + p] * L2E2);
            }
    }
    // ---- prefetch esv = exp2(2log2e * gs[k][h][p]) for all 9 taps
    float esv[9][2];
    #pragma unroll
    for (int k = 0; k < 9; ++k)
        #pragma unroll
        for (int mt = 0; mt < 2; ++mt) {
            int p = (mt0 + mt) * 16 + row;
            esv[k][mt] = __builtin_amdgcn_exp2f(gsb[k * HWSZ + h * WD + p] * L2E2);
        }

    // zero the two pad rows of xl (w = -1 and w = 128) once
    if (tid < 32)
        *(unsigned*)&lds.s.xl[0 * XSTR + tid * 2] = 0u;
    else if (tid < 64)
        *(unsigned*)&lds.s.xl[129 * XSTR + (tid - 32) * 2] = 0u;

    floatx4 acc[2][4];
    #pragma unroll
    for (int i = 0; i < 2; ++i)
        #pragma unroll
        for (int n = 0; n < 4; ++n)
            acc[i][n] = (floatx4){0.f, 0.f, 0.f, 0.f};

    #pragma unroll
    for (int dh = 0; dh < 3; ++dh) {
        const int hh = h + dh - 1;
        if ((unsigned)hh >= 128u) continue;   // block-uniform: taps contribute zero

        __syncthreads();   // previous MFMA phase done reading xl/wl

        // ---- stage W (pre-doubled bf16) for the 3 dw-taps of this dh
        if (wp) {
            #pragma unroll
            for (int it = 0; it < 6; ++it) {
                int idx = it * 256 + tid;            // 0..1535
                int dw = idx >> 9, o = (idx >> 3) & 63, cg = idx & 7;
                short8 v = *(const short8*)&wp[(dh * 3 + dw) * 4096 + o * 64 + cg * 8];
                *(short8*)&lds.s.wl[dw][o * XSTR + cg * 8] = v;
            }
        } else {
            #pragma unroll
            for (int it = 0; it < 48; ++it) {
                int idx = it * 256 + tid;            // 0..12287
                int dw = idx >> 12, o = (idx >> 6) & 63, c = idx & 63;
                lds.s.wl[dw][o * XSTR + c] = f2bf(2.0f * wgt[o * 576 + c * 9 + dh * 3 + dw]);
            }
        }

        // ---- stage x row hh: each thread owns 1 pixel x 8 consecutive channels.
        // Global: scalar loads, lanes 0..31 consecutive p -> 128B segments.
        // LDS: one ds_write_b128/it; granule = 9(p+1)+2g, 9 coprime 32 -> conflict-free.
        {
            const int g = tid >> 5;                  // channel-group 0..7 (c = 8g..8g+7)
            const float* xg = xb + (size_t)(8 * g) * HWSZ + hh * WD;
            #pragma unroll
            for (int it = 0; it < 4; ++it) {
                int p = it * 32 + (tid & 31);
                uintx4 pv;
                #pragma unroll
                for (int cc = 0; cc < 4; ++cc) {
                    float a  = xg[(size_t)(2 * cc) * HWSZ + p];
                    float b2 = xg[(size_t)(2 * cc + 1) * HWSZ + p];
                    pv[cc] = pack2bf(a, b2);
                }
                *(uintx4*)&lds.s.xl[(p + 1) * XSTR + g * 8] = pv;
            }
        }

        __syncthreads();

        // ---- 3 taps share this staging: no syncs between dw phases
        #pragma unroll
        for (int dw = 0; dw < 3; ++dw) {
            const int k = dh * 3 + dw;
            #pragma unroll
            for (int ks = 0; ks < 2; ++ks) {
                short8 af[2];
                #pragma unroll
                for (int mt = 0; mt < 2; ++mt) {
                    int wslot = (mt0 + mt) * 16 + row + dw;   // = p + dw, xl slot of w=p+dw-1
                    short8 raw = *(const short8*)&lds.s.xl[wslot * XSTR + ks * 32 + q * 8];
                    float es = esv[k][mt];
                    #pragma unroll
                    for (int jj = 0; jj < 4; ++jj) {
                        float d0 = fmaf(eg[mt][ks][2 * jj],     es, 1.0f);
                        float d1 = fmaf(eg[mt][ks][2 * jj + 1], es, 1.0f);
                        float r0 = __builtin_amdgcn_rcpf(d0);
                        float r1 = __builtin_amdgcn_rcpf(d1);
                        float x0 = bf2f(raw[2 * jj]);
                        float x1 = bf2f(raw[2 * jj + 1]);
                        float t0 = fmaf(-x0, r0, x0);   // x * u/(1+u), the 2 lives in w
                        float t1 = fmaf(-x1, r1, x1);
                        ((unsigned*)&af[mt])[jj] = pack2bf(t0, t1);
                    }
                }
                #pragma unroll
                for (int nt = 0; nt < 4; ++nt) {
                    short8 bv = *(const short8*)&lds.s.wl[dw][(nt * 16 + row) * XSTR + ks * 32 + q * 8];
                    acc[0][nt] = __builtin_amdgcn_mfma_f32_16x16x32_bf16(af[0], bv, acc[0][nt], 0, 0, 0);
                    acc[1][nt] = __builtin_amdgcn_mfma_f32_16x16x32_bf16(af[1], bv, acc[1][nt], 0, 0, 0);
                }
            }
        }
    }

    __syncthreads();

    // D layout: col(=o) = lane&15, rowD(=p) = (lane>>4)*4 + reg.
    // Vector b128 transpose writes: granule = 2*row + q (mod 32) -> <=2-way = free.
    #pragma unroll
    for (int i = 0; i < 2; ++i) {
        int prow = (mt0 + i) * 16 + q * 4;
        #pragma unroll
        for (int nt = 0; nt < 4; ++nt) {
            int o = nt * 16 + row;
            *(floatx4*)&lds.o[o * OSTR + prow] = acc[i][nt];
        }
    }

    __syncthreads();

    // coalesced float4 stores: out[b][o][h][0..127]; read granule = 2o+j -> 2-way = free
    float* outb = out + ((size_t)b * OD) * HWSZ + h * WD;
    #pragma unroll
    for (int it = 0; it < 8; ++it) {
        int idx = it * 256 + tid;              // 2048 float4s
        int o = idx >> 5, p4 = (idx & 31) * 4;
        *(floatx4*)&outb[(size_t)o * HWSZ + p4] = *(const floatx4*)&lds.o[o * OSTR + p4];
    }
}

extern "C" void kernel_launch(void* const* d_in, const int* in_sizes, int n_in,
                              void* d_out, int out_size, void* d_ws, size_t ws_size,
                              hipStream_t stream) {
    const float* x   = (const float*)d_in[0];
    const float* gcp = (const float*)d_in[1];
    const float* gsp = (const float*)d_in[2];
    const float* wgt = (const float*)d_in[3];
    float* out = (float*)d_out;

    const bool use_wp = ws_size >= (size_t)(9 * 64 * 64 * sizeof(unsigned short));
    unsigned short* wp = use_wp ? (unsigned short*)d_ws : nullptr;
    if (use_wp)
        prepack_w<<<dim3(144), dim3(256), 0, stream>>>(wgt, wp);
    paka_kernel<<<dim3(1024), dim3(256), 0, stream>>>(x, gcp, gsp, wgt, wp, out);
}